// Round 19
// baseline (3792.034 us; speedup 1.0000x reference)
//
#include <hip/hip_runtime.h>
#include <stdint.h>

#define BB   64
#define TT   512
#define KIN  256
#define HH   512
#define JGN  16     // j-groups: 32 cols each
#define BGN  4      // independent batch groups: 16 rows each
#define NJ2  32
#define NB   16
#define XPAD 260

typedef short bf16x8 __attribute__((ext_vector_type(8)));
typedef float f32x4  __attribute__((ext_vector_type(4)));

union U16x8 { unsigned short s[8]; bf16x8 v; };
union FU    { float f; unsigned u; };

__device__ __forceinline__ unsigned short f2bf(float f){
  FU v; v.f = f;
  unsigned r = v.u + 0x7fffu + ((v.u >> 16) & 1u);   // RNE
  return (unsigned short)(r >> 16);
}
__device__ __forceinline__ float bf2f(unsigned short s){
  FU v; v.u = ((unsigned)s) << 16; return v.f;
}
// 8 consecutive f32 -> single bf16 fragment (weights; RNE quantize)
__device__ __forceinline__ bf16x8 cvt8(const float* p){
  float4 a = ((const float4*)p)[0];
  float4 b = ((const float4*)p)[1];
  float f[8] = {a.x,a.y,a.z,a.w,b.x,b.y,b.z,b.w};
  U16x8 h;
  #pragma unroll
  for(int i=0;i<8;i++) h.s[i] = f2bf(f[i]);
  return h.v;
}
// 8 consecutive f32 -> split bf16 hi/lo fragments (activations; exact sum)
__device__ __forceinline__ void split8(const float* p, bf16x8& hi, bf16x8& lo){
  float4 a = ((const float4*)p)[0];
  float4 b = ((const float4*)p)[1];
  float f[8] = {a.x,a.y,a.z,a.w,b.x,b.y,b.z,b.w};
  U16x8 h,l;
  #pragma unroll
  for(int i=0;i<8;i++){
    unsigned short hb = f2bf(f[i]);
    l.s[i] = f2bf(f[i] - bf2f(hb));
    h.s[i] = hb;
  }
  hi = h.v; lo = l.v;
}
// two uint4 (8 packed u32, bf16hi|bf16lo) -> hi/lo fragments
__device__ __forceinline__ void unpackg(uint4 A, uint4 B, bf16x8& hi, bf16x8& lo){
  unsigned wv[8] = {A.x,A.y,A.z,A.w,B.x,B.y,B.z,B.w};
  U16x8 h,l;
  #pragma unroll
  for(int j=0;j<8;j++){
    h.s[j] = (unsigned short)(wv[j] >> 16);
    l.s[j] = (unsigned short)(wv[j] & 0xffffu);
  }
  hi = h.v; lo = l.v;
}

#define MFMA __builtin_amdgcn_mfma_f32_16x16x32_bf16

// SELF-CONTAINED coherent load: 4 x dwordx4 sc1 + vmcnt(0) in ONE asm block.
#define LD4W(Q0,Q1,Q2,Q3, BASE) \
  asm volatile( \
    "global_load_dwordx4 %0, %4, off sc1\n\t" \
    "global_load_dwordx4 %1, %4, off offset:16 sc1\n\t" \
    "global_load_dwordx4 %2, %4, off offset:128 sc1\n\t" \
    "global_load_dwordx4 %3, %4, off offset:144 sc1\n\t" \
    "s_waitcnt vmcnt(0)" \
    : "=&v"(Q0),"=&v"(Q1),"=&v"(Q2),"=&v"(Q3) \
    : "v"(BASE) : "memory")

__global__ __launch_bounds__(512, 1) void gru_scan(
    const float* __restrict__ x,  const float* __restrict__ Wm,
    const float* __restrict__ bW, const float* __restrict__ Um,
    const float* __restrict__ bU, float* __restrict__ out,
    unsigned* __restrict__ hbuf,  unsigned* __restrict__ flags)
{
  // scalar-split reduce buffers: [wave][ntile][reg(batch sub-row)][lane]
  __shared__ float redT [8][6][4][64];   // h partials  48 KB
  __shared__ float red2T[8][6][4][64];   // xg partials 48 KB
  __shared__ float xlds[NB][XPAD];       // x(t) staging (16.6 KB)

  const int tid  = threadIdx.x;
  const int u    = tid >> 6;        // wave 0..7 = K-eighth
  const int lane = tid & 63;
  const int col  = lane & 15;
  const int lg   = lane >> 4;
  const int ri   = u >> 1;          // gate phase: this wave's batch sub-row
  const int p    = u & 1;           // gate phase: this wave's j-parity
  const int bid  = blockIdx.x;
  const int bg   = bid >> 4;        // batch group 0..3 (independent chains)
  const int jg   = bid & 15;        // j-group 0..15
  const int j0   = jg * NJ2;
  const int b0g  = bg * NB;

  // per-wave flag slots: flags[(bg*16 + jg)*8 + wave]
  const int fpub = (bg*JGN + jg)*8 + u;

  // ---- persistent U/W fragments, single bf16 (72 VGPR, resident) ----
  bf16x8 BU[6][2], BW[6];
  #pragma unroll
  for(int nt=0; nt<6; nt++){
    int rl   = nt*16 + col;
    int g    = rl >> 5, jj = rl & 31;
    int grow = g*HH + j0 + jj;
    #pragma unroll
    for(int ks=0; ks<2; ks++)
      BU[nt][ks] = cvt8(Um + (size_t)grow*HH + u*64 + ks*32 + lg*8);
    BW[nt] = cvt8(Wm + (size_t)grow*KIN + u*32 + lg*8);
  }

  // ---- biases for this wave's gate slice (j = j0 + p*16 + col) ----
  float bsr, bsu, bwn, bun;
  {
    int r0 = j0 + p*16 + col;
    bsr = bW[r0]      + bU[r0];
    bsu = bW[HH + r0] + bU[HH + r0];
    bwn = bW[2*HH + r0];
    bun = bU[2*HH + r0];
  }

  float hreg = 0.f;   // this lane's h element: row b0g+lg*4+ri, col j0+p*16+col

  // ---- stage x(tt) rows [b0g, b0g+16): wave u stages rows 2u, 2u+1 ----
  auto stage_x = [&](int tt){
    #pragma unroll
    for(int i=0; i<2; i++){
      int bl = u*2 + i;
      const float* gp = x + ((size_t)(b0g + bl)*TT + tt)*KIN + lane*4;
      __builtin_amdgcn_global_load_lds(
        (const __attribute__((address_space(1))) unsigned*)(const void*)gp,
        (__attribute__((address_space(3))) unsigned*)(void*)&xlds[bl][0],
        16, 0, 0);
    }
  };

  // ---- per-wave poll: wave u needs j-blocks {2u,2u+1} x all 8 waves ----
  // 16 contiguous per-wave flags = one 64 B line
  auto pollw = [&](int tgt){
    const unsigned* fp = flags + (bg*JGN + 2*u)*8;
    while(true){
      unsigned f = __hip_atomic_load(&fp[lane & 15], __ATOMIC_RELAXED,
                                     __HIP_MEMORY_SCOPE_AGENT);
      if(__all((int)(f >= (unsigned)tgt))) break;
      __builtin_amdgcn_s_sleep(1);
    }
    __builtin_amdgcn_sched_barrier(0);
    asm volatile("" ::: "memory");
  };

  // ---- h-load + MFMA partials -> redT (scalar-split writes) ----
  auto h_mfma = [&](const unsigned* hb){
    const void* a0 = (const char*)(hb + (size_t)(b0g + col)*HH + u*64 + lg*8);
    uint4 q0,q1,q2,q3;
    LD4W(q0,q1,q2,q3, a0);
    __builtin_amdgcn_sched_barrier(0);
    f32x4 Ch[6];
    #pragma unroll
    for(int nt=0;nt<6;nt++) Ch[nt]=(f32x4){0,0,0,0};
    {
      bf16x8 ah, al;
      unpackg(q0,q1,ah,al);          // ks = 0
      #pragma unroll
      for(int nt=0; nt<6; nt++){
        Ch[nt] = MFMA(ah, BU[nt][0], Ch[nt], 0,0,0);
        Ch[nt] = MFMA(al, BU[nt][0], Ch[nt], 0,0,0);
      }
      unpackg(q2,q3,ah,al);          // ks = 1
      #pragma unroll
      for(int nt=0; nt<6; nt++){
        Ch[nt] = MFMA(ah, BU[nt][1], Ch[nt], 0,0,0);
        Ch[nt] = MFMA(al, BU[nt][1], Ch[nt], 0,0,0);
      }
    }
    #pragma unroll
    for(int nt=0;nt<6;nt++)
      #pragma unroll
      for(int r=0;r<4;r++)
        redT[u][nt][r][lane] = Ch[nt][r];
  };

  // ---- xg partials from LDS x -> red2T ----
  auto xg_partials = [&](){
    f32x4 Cx[6];
    #pragma unroll
    for(int nt=0;nt<6;nt++) Cx[nt]=(f32x4){0,0,0,0};
    bf16x8 ah, al;
    split8(&xlds[col][u*32 + lg*8], ah, al);
    #pragma unroll
    for(int nt=0; nt<6; nt++){
      Cx[nt] = MFMA(ah, BW[nt], Cx[nt], 0,0,0);
      Cx[nt] = MFMA(al, BW[nt], Cx[nt], 0,0,0);
    }
    #pragma unroll
    for(int nt=0;nt<6;nt++)
      #pragma unroll
      for(int r=0;r<4;r++)
        red2T[u][nt][r][lane] = Cx[nt][r];
  };

  // ---- all-wave xg reduce: 3 scalars for this lane's (row,col) ----
  auto xg_reduce = [&](float (&xg)[3]){
    #pragma unroll
    for(int gi=0; gi<3; gi++){
      int nt = gi*2 + p;
      float s0 = red2T[0][nt][ri][lane] + red2T[1][nt][ri][lane];
      float s1 = red2T[2][nt][ri][lane] + red2T[3][nt][ri][lane];
      float s2 = red2T[4][nt][ri][lane] + red2T[5][nt][ri][lane];
      float s3 = red2T[6][nt][ri][lane] + red2T[7][nt][ri][lane];
      xg[gi] = (s0 + s1) + (s2 + s3);
    }
  };

  // ---- all-wave gate phase: 1 output/lane; per-wave drain + flag publish ----
  auto gates = [&](unsigned* hw, int cell, const float (&xgf)[3], float& on){
    float hg[3];
    #pragma unroll
    for(int gi=0; gi<3; gi++){
      int nt = gi*2 + p;
      float s0 = redT[0][nt][ri][lane] + redT[1][nt][ri][lane];
      float s1 = redT[2][nt][ri][lane] + redT[3][nt][ri][lane];
      float s2 = redT[4][nt][ri][lane] + redT[5][nt][ri][lane];
      float s3 = redT[6][nt][ri][lane] + redT[7][nt][ri][lane];
      hg[gi] = (s0 + s1) + (s2 + s3);
    }
    float pr = xgf[0] + hg[0] + bsr;
    float pu = xgf[1] + hg[1] + bsu;
    float rg = __builtin_amdgcn_rcpf(1.f + __expf(-pr));
    float ug = __builtin_amdgcn_rcpf(1.f + __expf(-pu));
    float hn = hg[2] + bun;
    float z  = xgf[2] + bwn + rg*hn;
    z = fminf(fmaxf(z, -15.f), 15.f);
    float e  = __expf(2.f*z);
    float nn = (e - 1.f) * __builtin_amdgcn_rcpf(e + 1.f);   // tanh(z)
    float hnew = ug*hreg + (1.f - ug)*nn;
    hreg = hnew;
    on   = hnew;
    unsigned short h16 = f2bf(hnew);
    unsigned short l16 = f2bf(hnew - bf2f(h16));
    __hip_atomic_store(&hw[(size_t)(b0g + lg*4 + ri)*HH + j0 + p*16 + col],
                       ((unsigned)h16 << 16) | (unsigned)l16,
                       __ATOMIC_RELAXED, __HIP_MEMORY_SCOPE_AGENT);
    // drain THIS wave's h-store to LLC, then publish THIS wave's flag.
    // No block barrier on the inter-block critical path.
    asm volatile("s_waitcnt vmcnt(0)" ::: "memory");
    if(lane == 0)
      __hip_atomic_store(&flags[fpub], (unsigned)cell + 1u,
                         __ATOMIC_RELAXED, __HIP_MEMORY_SCOPE_AGENT);
  };

  auto out_store = [&](int cell, float on){
    out[((size_t)cell*BB + b0g + lg*4 + ri)*HH + j0 + p*16 + col] = on;
  };

  unsigned* hb0 = hbuf;
  unsigned* hb1 = hbuf + (size_t)BB*HH;

  float xgf[3] = {0,0,0}, xgn[3] = {0,0,0};
  float on0 = 0.f, on1 = 0.f;

  // prologue: x(0) -> xgf ; then pre-stage x(1)
  stage_x(0);
  __syncthreads();
  xg_partials();
  __syncthreads();
  xg_reduce(xgf);
  stage_x(1);
  __syncthreads();

  for(int t=0; t<TT; t++){
    // ==== EVEN cell 2t: read buf0, write buf1 ====
    pollw(2*t);
    h_mfma(hb0);
    if(t+1 < TT) xg_partials();        // x(t+1), staged 2 cells ago
    __syncthreads();                   // sync1: redT/red2T ready; all polls done
    gates(hb1, 2*t, xgf, on0);         // stores + per-wave drain + flag publish
    if(t+1 < TT) xg_reduce(xgn);       // off critical path (post-publish)
    out_store(2*t, on0);
    __syncthreads();                   // sync2: redT WAR vs next h_mfma

    // ==== ODD cell 2t+1: read buf1, write buf0 ====
    if(t+2 < TT) stage_x(t+2);         // drained by odd LD4W + barriers
    pollw(2*t + 1);
    h_mfma(hb1);
    __syncthreads();                   // sync1
    gates(hb0, 2*t + 1, xgf, on1);
    out_store(2*t + 1, on1);
    __syncthreads();                   // sync2

    xgf[0] = xgn[0]; xgf[1] = xgn[1]; xgf[2] = xgn[2];
  }
}

extern "C" void kernel_launch(void* const* d_in, const int* in_sizes, int n_in,
                              void* d_out, int out_size, void* d_ws, size_t ws_size,
                              hipStream_t stream) {
  const float* x  = (const float*)d_in[0];
  const float* Wm = (const float*)d_in[1];
  const float* bW = (const float*)d_in[2];
  const float* Um = (const float*)d_in[3];
  const float* bU = (const float*)d_in[4];
  float* out = (float*)d_out;

  // ws layout: hbuf[2][64][512] u32 (256 KB) + flags[64*8] u32 (2 KB)
  unsigned* hbuf  = (unsigned*)d_ws;
  unsigned* flags = (unsigned*)((char*)d_ws + 2*BB*HH*sizeof(unsigned));
  (void)hipMemsetAsync(d_ws, 0, 2*BB*HH*sizeof(unsigned) + 4096, stream);

  gru_scan<<<BGN*JGN, 512, 0, stream>>>(x, Wm, bW, Um, bU, out, hbuf, flags);
}

// Round 20
// 3061.408 us; speedup vs baseline: 1.2387x; 1.2387x over previous
//
#include <hip/hip_runtime.h>
#include <stdint.h>

#define BB   64
#define TT   512
#define KIN  256
#define HH   512
#define JGN  16     // j-groups: 32 cols each
#define BGN  4      // independent batch groups: 16 rows each
#define NJ2  32
#define NB   16
#define XPAD 260

typedef short bf16x8 __attribute__((ext_vector_type(8)));
typedef float f32x4  __attribute__((ext_vector_type(4)));

union U16x8 { unsigned short s[8]; bf16x8 v; };
union FU    { float f; unsigned u; };

__device__ __forceinline__ unsigned short f2bf(float f){
  FU v; v.f = f;
  unsigned r = v.u + 0x7fffu + ((v.u >> 16) & 1u);   // RNE
  return (unsigned short)(r >> 16);
}
__device__ __forceinline__ float bf2f(unsigned short s){
  FU v; v.u = ((unsigned)s) << 16; return v.f;
}
// 8 consecutive f32 -> single bf16 fragment (weights; RNE quantize)
__device__ __forceinline__ bf16x8 cvt8(const float* p){
  float4 a = ((const float4*)p)[0];
  float4 b = ((const float4*)p)[1];
  float f[8] = {a.x,a.y,a.z,a.w,b.x,b.y,b.z,b.w};
  U16x8 h;
  #pragma unroll
  for(int i=0;i<8;i++) h.s[i] = f2bf(f[i]);
  return h.v;
}
// 8 consecutive f32 -> split bf16 hi/lo fragments (activations; exact sum)
__device__ __forceinline__ void split8(const float* p, bf16x8& hi, bf16x8& lo){
  float4 a = ((const float4*)p)[0];
  float4 b = ((const float4*)p)[1];
  float f[8] = {a.x,a.y,a.z,a.w,b.x,b.y,b.z,b.w};
  U16x8 h,l;
  #pragma unroll
  for(int i=0;i<8;i++){
    unsigned short hb = f2bf(f[i]);
    l.s[i] = f2bf(f[i] - bf2f(hb));
    h.s[i] = hb;
  }
  hi = h.v; lo = l.v;
}
// two uint4 (8 packed u32, bf16hi|bf16lo) -> hi/lo fragments
__device__ __forceinline__ void unpackg(uint4 A, uint4 B, bf16x8& hi, bf16x8& lo){
  unsigned wv[8] = {A.x,A.y,A.z,A.w,B.x,B.y,B.z,B.w};
  U16x8 h,l;
  #pragma unroll
  for(int j=0;j<8;j++){
    h.s[j] = (unsigned short)(wv[j] >> 16);
    l.s[j] = (unsigned short)(wv[j] & 0xffffu);
  }
  hi = h.v; lo = l.v;
}

#define MFMA __builtin_amdgcn_mfma_f32_16x16x32_bf16

// SELF-CONTAINED coherent load: 4 x dwordx4 sc1 + vmcnt(0) in ONE asm block.
#define LD4W(Q0,Q1,Q2,Q3, BASE) \
  asm volatile( \
    "global_load_dwordx4 %0, %4, off sc1\n\t" \
    "global_load_dwordx4 %1, %4, off offset:16 sc1\n\t" \
    "global_load_dwordx4 %2, %4, off offset:128 sc1\n\t" \
    "global_load_dwordx4 %3, %4, off offset:144 sc1\n\t" \
    "s_waitcnt vmcnt(0)" \
    : "=&v"(Q0),"=&v"(Q1),"=&v"(Q2),"=&v"(Q3) \
    : "v"(BASE) : "memory")

__global__ __launch_bounds__(512, 1) void gru_scan(
    const float* __restrict__ x,  const float* __restrict__ Wm,
    const float* __restrict__ bW, const float* __restrict__ Um,
    const float* __restrict__ bU, float* __restrict__ out,
    unsigned* __restrict__ hbuf,  unsigned* __restrict__ flags)
{
  // scalar-split reduce buffers: [wave][ntile][reg(batch sub-row)][lane]
  __shared__ float redT [8][6][4][64];   // h partials  48 KB
  __shared__ float red2T[8][6][4][64];   // xg partials 48 KB
  __shared__ float xlds[NB][XPAD];       // x(t) staging (16.6 KB)

  const int tid  = threadIdx.x;
  const int u    = tid >> 6;        // wave 0..7 = K-eighth
  const int lane = tid & 63;
  const int col  = lane & 15;
  const int lg   = lane >> 4;
  const int ri   = u >> 1;          // gate phase: this wave's batch sub-row
  const int p    = u & 1;           // gate phase: this wave's j-parity
  const int bid  = blockIdx.x;
  const int bg   = bid >> 4;        // batch group 0..3 (independent chains)
  const int jg   = bid & 15;        // j-group 0..15
  const int j0   = jg * NJ2;
  const int b0g  = bg * NB;

  // ---- persistent U/W fragments, single bf16 (72 VGPR, resident) ----
  bf16x8 BU[6][2], BW[6];
  #pragma unroll
  for(int nt=0; nt<6; nt++){
    int rl   = nt*16 + col;
    int g    = rl >> 5, jj = rl & 31;
    int grow = g*HH + j0 + jj;
    #pragma unroll
    for(int ks=0; ks<2; ks++)
      BU[nt][ks] = cvt8(Um + (size_t)grow*HH + u*64 + ks*32 + lg*8);
    BW[nt] = cvt8(Wm + (size_t)grow*KIN + u*32 + lg*8);
  }

  // ---- biases for this wave's gate slice (j = j0 + p*16 + col) ----
  float bsr, bsu, bwn, bun;
  {
    int r0 = j0 + p*16 + col;
    bsr = bW[r0]      + bU[r0];
    bsu = bW[HH + r0] + bU[HH + r0];
    bwn = bW[2*HH + r0];
    bun = bU[2*HH + r0];
  }

  float hreg = 0.f;   // this lane's h element: row b0g+lg*4+ri, col j0+p*16+col

  // ---- stage x(tt) rows [b0g, b0g+16): wave u stages rows 2u, 2u+1 ----
  auto stage_x = [&](int tt){
    #pragma unroll
    for(int i=0; i<2; i++){
      int bl = u*2 + i;
      const float* gp = x + ((size_t)(b0g + bl)*TT + tt)*KIN + lane*4;
      __builtin_amdgcn_global_load_lds(
        (const __attribute__((address_space(1))) unsigned*)(const void*)gp,
        (__attribute__((address_space(3))) unsigned*)(void*)&xlds[bl][0],
        16, 0, 0);
    }
  };

  // ---- per-wave poll: wave u needs only j-blocks {2u, 2u+1} of its group ----
  auto pollw = [&](int tgt){
    const unsigned* fp = flags + bg*JGN + 2*u;
    while(true){
      unsigned f = __hip_atomic_load(&fp[lane & 1], __ATOMIC_RELAXED,
                                     __HIP_MEMORY_SCOPE_AGENT);
      if(__all((int)(f >= (unsigned)tgt))) break;
      __builtin_amdgcn_s_sleep(1);
    }
    __builtin_amdgcn_sched_barrier(0);
    asm volatile("" ::: "memory");
  };

  // ---- h-load + MFMA partials -> redT (scalar-split writes) ----
  auto h_mfma = [&](const unsigned* hb){
    const void* a0 = (const char*)(hb + (size_t)(b0g + col)*HH + u*64 + lg*8);
    uint4 q0,q1,q2,q3;
    LD4W(q0,q1,q2,q3, a0);
    __builtin_amdgcn_sched_barrier(0);
    f32x4 Ch[6];
    #pragma unroll
    for(int nt=0;nt<6;nt++) Ch[nt]=(f32x4){0,0,0,0};
    {
      bf16x8 ah, al;
      unpackg(q0,q1,ah,al);          // ks = 0
      #pragma unroll
      for(int nt=0; nt<6; nt++){
        Ch[nt] = MFMA(ah, BU[nt][0], Ch[nt], 0,0,0);
        Ch[nt] = MFMA(al, BU[nt][0], Ch[nt], 0,0,0);
      }
      unpackg(q2,q3,ah,al);          // ks = 1
      #pragma unroll
      for(int nt=0; nt<6; nt++){
        Ch[nt] = MFMA(ah, BU[nt][1], Ch[nt], 0,0,0);
        Ch[nt] = MFMA(al, BU[nt][1], Ch[nt], 0,0,0);
      }
    }
    #pragma unroll
    for(int nt=0;nt<6;nt++)
      #pragma unroll
      for(int r=0;r<4;r++)
        redT[u][nt][r][lane] = Ch[nt][r];
  };

  // ---- xg partials from LDS x -> red2T ----
  auto xg_partials = [&](){
    f32x4 Cx[6];
    #pragma unroll
    for(int nt=0;nt<6;nt++) Cx[nt]=(f32x4){0,0,0,0};
    bf16x8 ah, al;
    split8(&xlds[col][u*32 + lg*8], ah, al);
    #pragma unroll
    for(int nt=0; nt<6; nt++){
      Cx[nt] = MFMA(ah, BW[nt], Cx[nt], 0,0,0);
      Cx[nt] = MFMA(al, BW[nt], Cx[nt], 0,0,0);
    }
    #pragma unroll
    for(int nt=0;nt<6;nt++)
      #pragma unroll
      for(int r=0;r<4;r++)
        red2T[u][nt][r][lane] = Cx[nt][r];
  };

  // ---- all-wave xg reduce: 3 scalars for this lane's (row,col) ----
  auto xg_reduce = [&](float (&xg)[3]){
    #pragma unroll
    for(int gi=0; gi<3; gi++){
      int nt = gi*2 + p;
      float s0 = red2T[0][nt][ri][lane] + red2T[1][nt][ri][lane];
      float s1 = red2T[2][nt][ri][lane] + red2T[3][nt][ri][lane];
      float s2 = red2T[4][nt][ri][lane] + red2T[5][nt][ri][lane];
      float s3 = red2T[6][nt][ri][lane] + red2T[7][nt][ri][lane];
      xg[gi] = (s0 + s1) + (s2 + s3);
    }
  };

  // ---- all-wave gate phase: 1 output/lane ----
  auto gates = [&](unsigned* hw, const float (&xgf)[3], float& on){
    float hg[3];
    #pragma unroll
    for(int gi=0; gi<3; gi++){
      int nt = gi*2 + p;
      float s0 = redT[0][nt][ri][lane] + redT[1][nt][ri][lane];
      float s1 = redT[2][nt][ri][lane] + redT[3][nt][ri][lane];
      float s2 = redT[4][nt][ri][lane] + redT[5][nt][ri][lane];
      float s3 = redT[6][nt][ri][lane] + redT[7][nt][ri][lane];
      hg[gi] = (s0 + s1) + (s2 + s3);
    }
    float pr = xgf[0] + hg[0] + bsr;
    float pu = xgf[1] + hg[1] + bsu;
    float rg = __builtin_amdgcn_rcpf(1.f + __expf(-pr));
    float ug = __builtin_amdgcn_rcpf(1.f + __expf(-pu));
    float hn = hg[2] + bun;
    float z  = xgf[2] + bwn + rg*hn;
    z = fminf(fmaxf(z, -15.f), 15.f);
    float e  = __expf(2.f*z);
    float nn = (e - 1.f) * __builtin_amdgcn_rcpf(e + 1.f);   // tanh(z)
    float hnew = ug*hreg + (1.f - ug)*nn;
    hreg = hnew;
    on   = hnew;
    unsigned short h16 = f2bf(hnew);
    unsigned short l16 = f2bf(hnew - bf2f(h16));
    __hip_atomic_store(&hw[(size_t)(b0g + lg*4 + ri)*HH + j0 + p*16 + col],
                       ((unsigned)h16 << 16) | (unsigned)l16,
                       __ATOMIC_RELAXED, __HIP_MEMORY_SCOPE_AGENT);
  };

  auto out_store = [&](int cell, float on){
    out[((size_t)cell*BB + b0g + lg*4 + ri)*HH + j0 + p*16 + col] = on;
  };

  unsigned* hb0 = hbuf;
  unsigned* hb1 = hbuf + (size_t)BB*HH;

  float xgf[3] = {0,0,0}, xgn[3] = {0,0,0};
  float on0 = 0.f, on1 = 0.f;

  // prologue: x(0) -> xgf ; then pre-stage x(1)
  stage_x(0);
  __syncthreads();
  xg_partials();
  __syncthreads();
  xg_reduce(xgf);
  stage_x(1);
  __syncthreads();

  for(int t=0; t<TT; t++){
    // ==== EVEN cell 2t: read buf0, write buf1 ====
    pollw(2*t);
    h_mfma(hb0);
    if(t+1 < TT) xg_partials();        // x(t+1), staged 2 cells ago
    __syncthreads();                   // sync1
    gates(hb1, xgf, on0);
    __syncthreads();                   // sync2 (vmcnt drain incl. h-stores)
    if(tid == 0)
      __hip_atomic_store(&flags[bid & 63], (unsigned)(2*t) + 1u,
                         __ATOMIC_RELAXED, __HIP_MEMORY_SCOPE_AGENT);
    if(t+1 < TT) xg_reduce(xgn);
    out_store(2*t, on0);

    // ==== ODD cell 2t+1: read buf1, write buf0 ====
    if(t+2 < TT) stage_x(t+2);         // drained by odd sync1
    pollw(2*t + 1);
    h_mfma(hb1);
    __syncthreads();                   // sync1
    gates(hb0, xgf, on1);
    __syncthreads();                   // sync2 (drain)
    if(tid == 0)
      __hip_atomic_store(&flags[bid & 63], (unsigned)(2*t) + 2u,
                         __ATOMIC_RELAXED, __HIP_MEMORY_SCOPE_AGENT);
    out_store(2*t + 1, on1);

    xgf[0] = xgn[0]; xgf[1] = xgn[1]; xgf[2] = xgn[2];
  }
}

extern "C" void kernel_launch(void* const* d_in, const int* in_sizes, int n_in,
                              void* d_out, int out_size, void* d_ws, size_t ws_size,
                              hipStream_t stream) {
  const float* x  = (const float*)d_in[0];
  const float* Wm = (const float*)d_in[1];
  const float* bW = (const float*)d_in[2];
  const float* Um = (const float*)d_in[3];
  const float* bU = (const float*)d_in[4];
  float* out = (float*)d_out;

  // ws layout: hbuf[2][64][512] u32 (256 KB) + flags[64] u32
  unsigned* hbuf  = (unsigned*)d_ws;
  unsigned* flags = (unsigned*)((char*)d_ws + 2*BB*HH*sizeof(unsigned));
  (void)hipMemsetAsync(d_ws, 0, 2*BB*HH*sizeof(unsigned) + 256, stream);

  gru_scan<<<BGN*JGN, 512, 0, stream>>>(x, Wm, bW, Um, bU, out, hbuf, flags);
}